// Round 1
// baseline (56.917 us; speedup 1.0000x reference)
//
#include <hip/hip_runtime.h>
#include <math.h>

#define BB 32
#define SS 2048
#define HH 1024
#define RR 64
#define H4 (HH/4)

// ---------------- mask dtype classifier ----------------
// rubric_mask is bool in the reference; the harness may store it as
// uint8 (numpy bool), int32, or float32. Inspect the first B*R bytes
// (safe under all layouts: uint8 => exactly 2048 B, int32/f32 => 8192 B).
//   uint8 bool : ~80% nonzero bytes at random positions -> nonzero at i%4==1
//   int32 0/1  : bytes [x,0,0,0] -> all i%4!=0 bytes are 0
//   f32 0.0/1.0: bytes [0,0,0x80,0x3F] -> nonzero at i%4==3, zero at i%4==1
// flag: 0 = int32, 1 = uint8, 2 = float32
__global__ void classify_mask_k(const unsigned char* m, int* flag) {
    __shared__ int c1s, c3s;
    int t = threadIdx.x;
    if (t == 0) { c1s = 0; c3s = 0; }
    __syncthreads();
    int c1 = 0, c3 = 0;
    for (int i = t; i < BB * RR; i += 256) {
        if (m[i]) {
            int p = i & 3;
            if (p == 1) c1 = 1;
            else if (p == 3) c3 = 1;
        }
    }
    if (c1) atomicOr(&c1s, 1);
    if (c3) atomicOr(&c3s, 1);
    __syncthreads();
    if (t == 0) *flag = c1s ? 1 : (c3s ? 2 : 0);
}

__device__ __forceinline__ bool read_mask(const void* m, int flag, int i) {
    if (flag == 1) return ((const unsigned char*)m)[i] != 0;
    if (flag == 2) return ((const float*)m)[i] != 0.0f;
    return ((const int*)m)[i] != 0;
}

// ---------------- answer span mean pooling ----------------
// grid = B, block = 256. Thread t owns float4 chunk t of the H=1024 row.
__global__ void answer_pool_k(const float4* __restrict__ seq,
                              const int* __restrict__ aspan,
                              float4* __restrict__ aemb) {
    int b = blockIdx.x, t = threadIdx.x;
    int s0 = aspan[2 * b], s1 = aspan[2 * b + 1];
    int len = s1 - s0; if (len < 1) len = 1;
    float4 acc = make_float4(0.f, 0.f, 0.f, 0.f);
    const float4* base = seq + (size_t)b * SS * H4 + t;
    for (int s = s0; s < s1; ++s) {
        float4 x = base[(size_t)s * H4];
        acc.x += x.x; acc.y += x.y; acc.z += x.z; acc.w += x.w;
    }
    float inv = 1.0f / (float)len;
    acc.x *= inv; acc.y *= inv; acc.z *= inv; acc.w *= inv;
    aemb[b * H4 + t] = acc;
}

// ---------------- v[b,h] = sum_k W[h,k] * a[b,k] ----------------
// grid = H (one block per W row), block = 256 (float4 chunk per thread).
__global__ void bilinear_matvec_k(const float4* __restrict__ Wm,
                                  const float4* __restrict__ aemb,
                                  float* __restrict__ v) {
    int h = blockIdx.x, t = threadIdx.x;
    float4 w = Wm[(size_t)h * H4 + t];
    __shared__ float red[4][BB];
    int wave = t >> 6, lane = t & 63;
    for (int b = 0; b < BB; ++b) {
        float4 a = aemb[b * H4 + t];
        float p = w.x * a.x + w.y * a.y + w.z * a.z + w.w * a.w;
        for (int off = 32; off; off >>= 1) p += __shfl_down(p, off);
        if (lane == 0) red[wave][b] = p;
    }
    __syncthreads();
    if (t < BB) {
        float s = red[0][t] + red[1][t] + red[2][t] + red[3][t];
        v[t * HH + h] = s;   // v[b=t][h]
    }
}

// ---------------- rubric scores ----------------
// grid = B*R, block = 256. scores[b,r] = (1/len) * sum_{s in span} seq[b,s].v[b] + bias
__global__ void rubric_scores_k(const float4* __restrict__ seq,
                                const float4* __restrict__ v4,
                                const int* __restrict__ rspan,
                                const void* __restrict__ mask,
                                const int* __restrict__ flagp,
                                const float* __restrict__ bias,
                                float* __restrict__ scores) {
    int blk = blockIdx.x;
    int b = blk >> 6;      // / R
    int r = blk & (RR - 1);
    int t = threadIdx.x;
    int flag = *flagp;
    bool mk = read_mask(mask, flag, b * RR + r);
    if (!mk) {
        if (t == 0) scores[b * RR + r] = -INFINITY;
        return;
    }
    int s0 = rspan[(b * RR + r) * 2], s1 = rspan[(b * RR + r) * 2 + 1];
    int len = s1 - s0; if (len < 1) len = 1;
    float4 vv = v4[b * H4 + t];
    float p = 0.f;
    const float4* base = seq + (size_t)b * SS * H4 + t;
    for (int s = s0; s < s1; ++s) {
        float4 x = base[(size_t)s * H4];
        p += x.x * vv.x + x.y * vv.y + x.z * vv.z + x.w * vv.w;
    }
    __shared__ float red[4];
    int wave = t >> 6, lane = t & 63;
    for (int off = 32; off; off >>= 1) p += __shfl_down(p, off);
    if (lane == 0) red[wave] = p;
    __syncthreads();
    if (t == 0)
        scores[b * RR + r] = red[0] + red[1] + red[2] + red[3] + 
                             0.f + ((red[0]+red[1]+red[2]+red[3]) == 0.f ? 0.f : 0.f),
        scores[b * RR + r] = (red[0] + red[1] + red[2] + red[3]) / (float)len + bias[0];
}

// ---------------- softmax over R=64 per batch ----------------
// grid = B, block = 64 (one wave).
__global__ void softmax_k(const float* __restrict__ scores, float* __restrict__ out) {
    int b = blockIdx.x, r = threadIdx.x;
    float x = scores[b * RR + r];
    float m = x;
    for (int off = 32; off; off >>= 1) m = fmaxf(m, __shfl_xor(m, off));
    float e = expf(x - m);          // masked lanes: exp(-inf - m) = 0
    float s = e;
    for (int off = 32; off; off >>= 1) s += __shfl_xor(s, off);
    out[b * RR + r] = e / s;
}

extern "C" void kernel_launch(void* const* d_in, const int* in_sizes, int n_in,
                              void* d_out, int out_size, void* d_ws, size_t ws_size,
                              hipStream_t stream) {
    const float* seq  = (const float*)d_in[0];
    const float* Wm   = (const float*)d_in[1];
    const float* bias = (const float*)d_in[2];
    const int*   rspan = (const int*)d_in[3];
    const int*   aspan = (const int*)d_in[4];
    const void*  mask  = d_in[5];

    char* ws = (char*)d_ws;
    int*   flag   = (int*)ws;
    float* aemb   = (float*)(ws + 256);
    float* v      = aemb + BB * HH;
    float* scores = v + BB * HH;

    classify_mask_k<<<1, 256, 0, stream>>>((const unsigned char*)mask, flag);
    answer_pool_k<<<BB, 256, 0, stream>>>((const float4*)seq, aspan, (float4*)aemb);
    bilinear_matvec_k<<<HH, 256, 0, stream>>>((const float4*)Wm, (const float4*)aemb, v);
    rubric_scores_k<<<BB * RR, 256, 0, stream>>>((const float4*)seq, (const float4*)v,
                                                 rspan, mask, flag, bias, scores);
    softmax_k<<<BB, 64, 0, stream>>>(scores, (float*)d_out);
}